// Round 11
// baseline (510.511 us; speedup 1.0000x reference)
//
#include <hip/hip_runtime.h>

// GCN on MI355X.
// R2: CSR gather. R3-R10: GEMM -> f16 MFMA, glds triple-buffer counted-vmcnt
// pipeline. Gathers at L3-fabric roofline (819MB logical @ 7.0TB/s = 117us).
// R10 counters exposed __amd_rocclr_fillBufferAligned (hipMemsetAsync of 400KB
// deg) at 118us/replay.
// R11: replace memset with own zero kernel; fuse cvt_x+wtrans into one prep
// kernel; gather h-stores nontemporal (don't pollute L2 vs y16 random reads).

#define N_NODES 100000
constexpr int D_IN  = 512;
constexpr int D_H   = 256;
constexpr int D_OUT = 128;
constexpr int M_PAD = 100096;   // 782*128

typedef _Float16 f16x8 __attribute__((ext_vector_type(8)));
typedef _Float16 f16x4 __attribute__((ext_vector_type(4)));
typedef float f32x4 __attribute__((ext_vector_type(4)));

#define GLD16(SRC, DST) __builtin_amdgcn_global_load_lds(                      \
    (const __attribute__((address_space(1))) void*)(SRC),                      \
    (__attribute__((address_space(3))) void*)(DST), 16, 0, 0)

// ---------- deg zero (replaces rocclr fillBuffer: was 118us in-graph) ----------
__global__ __launch_bounds__(256) void zero_deg_k(int* __restrict__ deg) {
  int i = (blockIdx.x * 256 + threadIdx.x) * 4;
  if (i < N_NODES) *(int4*)(deg + i) = make_int4(0, 0, 0, 0);  // N%4==0
}

// ---------- fused prep: x->f16 (padded) + all weight transposes ----------
constexpr int CVT_BLOCKS = (M_PAD * (D_IN / 8)) / 256;  // 25024
__global__ __launch_bounds__(256) void prep_k(const float* __restrict__ x,
                                              _Float16* __restrict__ x16,
                                              const float* __restrict__ W1,
                                              const float* __restrict__ W2,
                                              const float* __restrict__ FC,
                                              _Float16* __restrict__ w1t,
                                              _Float16* __restrict__ w2t,
                                              _Float16* __restrict__ fct) {
  if (blockIdx.x < CVT_BLOCKS) {
    size_t i = ((size_t)blockIdx.x * 256 + threadIdx.x) * 8;
    const size_t valid = (size_t)N_NODES * D_IN;
    if (i < valid) {
      float4 a = *(const float4*)(x + i);
      float4 b = *(const float4*)(x + i + 4);
      f16x8 v;
      v[0] = (_Float16)a.x; v[1] = (_Float16)a.y;
      v[2] = (_Float16)a.z; v[3] = (_Float16)a.w;
      v[4] = (_Float16)b.x; v[5] = (_Float16)b.y;
      v[6] = (_Float16)b.z; v[7] = (_Float16)b.w;
      *(f16x8*)(x16 + i) = v;
    } else if (i < (size_t)M_PAD * D_IN) {
      *(f16x8*)(x16 + i) = (f16x8){0, 0, 0, 0, 0, 0, 0, 0};
    }
    return;
  }
  int i = (blockIdx.x - CVT_BLOCKS) * 256 + threadIdx.x;
  if (i < 131072) {                       // W1: 512x256
    int k = i >> 8, n = i & 255;
    w1t[(size_t)n * 512 + k] = (_Float16)W1[i];
  } else if (i < 196608) {                // W2: 256x256
    int j = i - 131072;
    int k = j >> 8, n = j & 255;
    w2t[(size_t)n * 256 + k] = (_Float16)W2[j];
  } else if (i < 229376) {                // fc_w: 256x128
    int j = i - 196608;
    int k = j >> 7, n = j & 127;
    fct[(size_t)n * 256 + k] = (_Float16)FC[j];
  }
}

// ---------- CSR build ----------
__global__ __launch_bounds__(256) void deg_count_k(const int* __restrict__ dst,
                                                   int* __restrict__ deg,
                                                   int* __restrict__ pe, int E) {
  int i = (blockIdx.x * 256 + threadIdx.x) * 4;
  if (i + 3 < E) {
    int4 d = *(const int4*)(dst + i);
    int4 p;
    p.x = atomicAdd(&deg[d.x], 1);
    p.y = atomicAdd(&deg[d.y], 1);
    p.z = atomicAdd(&deg[d.z], 1);
    p.w = atomicAdd(&deg[d.w], 1);
    *(int4*)(pe + i) = p;
  } else {
    for (int t = i; t < E; ++t) pe[t] = atomicAdd(&deg[dst[t]], 1);
  }
}

__global__ __launch_bounds__(256) void scan1_k(const int* __restrict__ deg,
                                               int* __restrict__ off,
                                               int* __restrict__ bsum,
                                               float* __restrict__ dis, int n) {
  __shared__ int ts[256];
  const int tid = threadIdx.x;
  const int base = blockIdx.x * 1024 + tid * 4;
  int v[4];
#pragma unroll
  for (int t = 0; t < 4; ++t) v[t] = (base + t < n) ? deg[base + t] : 0;
#pragma unroll
  for (int t = 0; t < 4; ++t)
    if (base + t < n) dis[base + t] = rsqrtf((float)v[t] + 1.0f);
  const int tot = v[0] + v[1] + v[2] + v[3];
  ts[tid] = tot;
  __syncthreads();
  for (int o = 1; o < 256; o <<= 1) {
    int t = (tid >= o) ? ts[tid - o] : 0;
    __syncthreads();
    ts[tid] += t;
    __syncthreads();
  }
  int run = ts[tid] - tot;
#pragma unroll
  for (int t = 0; t < 4; ++t) {
    if (base + t < n) off[base + t] = run;
    run += v[t];
  }
  if (tid == 255) bsum[blockIdx.x] = ts[255];
}

__global__ __launch_bounds__(128) void scan2_k(int* __restrict__ bsum, int nb) {
  __shared__ int ts[128];
  const int tid = threadIdx.x;
  const int v = (tid < nb) ? bsum[tid] : 0;
  ts[tid] = v;
  __syncthreads();
  for (int o = 1; o < 128; o <<= 1) {
    int t = (tid >= o) ? ts[tid - o] : 0;
    __syncthreads();
    ts[tid] += t;
    __syncthreads();
  }
  if (tid < nb) bsum[tid] = ts[tid] - v;
}

__global__ __launch_bounds__(256) void fill_k(const int* __restrict__ src,
                                              const int* __restrict__ dst,
                                              const int* __restrict__ pe,
                                              const int* __restrict__ off,
                                              const int* __restrict__ bsum,
                                              int* __restrict__ ssorted, int E) {
  int i = (blockIdx.x * 256 + threadIdx.x) * 4;
  if (i + 3 < E) {
    int4 s = *(const int4*)(src + i);
    int4 d = *(const int4*)(dst + i);
    int4 p = *(const int4*)(pe + i);
    ssorted[off[d.x] + bsum[d.x >> 10] + p.x] = s.x;
    ssorted[off[d.y] + bsum[d.y >> 10] + p.y] = s.y;
    ssorted[off[d.z] + bsum[d.z >> 10] + p.z] = s.z;
    ssorted[off[d.w] + bsum[d.w >> 10] + p.w] = s.w;
  } else {
    for (int t = i; t < E; ++t) {
      int d = dst[t];
      ssorted[off[d] + bsum[d >> 10] + pe[t]] = src[t];
    }
  }
}

// ---------- triple-buffered glds f16 MFMA GEMM, counted vmcnt (R10) ----------
template<int BN, bool OUT_Y>
__global__ __launch_bounds__(512, 4) void gemm_glds_k(
    const _Float16* __restrict__ A16,
    const _Float16* __restrict__ Bt,
    const float* __restrict__ bias,
    const float* __restrict__ dis,
    float* __restrict__ C,
    _Float16* __restrict__ Y,
    int M, int K) {
  constexpr int BM = 128, BK = 32;
  constexpr int FN  = BN / 64;
  constexpr int NBI = BN / 128;
  constexpr int ASZ = BM * BK;
  constexpr int BSZ = BN * BK;
  constexpr int EPAD = 4;

  __shared__ __align__(16) _Float16 smem[3 * (ASZ + BSZ)];  // 72 KB (BN=256)
  _Float16* As = smem;
  _Float16* Bs = smem + 3 * ASZ;
  float* epi = (float*)smem;

  const int tid  = threadIdx.x;
  const int w    = tid >> 6, lane = tid & 63;
  const int wm   = w >> 2, wn = w & 3;
  const int l15  = lane & 15, l16 = lane >> 4;
  const int row0 = blockIdx.y * BM;

  const int lr = lane >> 2, lg = lane & 3;
  const int arow  = w * 16 + lr;
  const int brow0 = w * (NBI * 16) + lr;
  const int brow1 = brow0 + 16;
  const _Float16* srcA  = A16 + (size_t)(row0 + arow) * K + ((lg ^ (arow & 3)) << 3);
  const _Float16* srcB0 = Bt + (size_t)brow0 * K + ((lg ^ (brow0 & 3)) << 3);
  const _Float16* srcB1 = Bt + (size_t)brow1 * K + ((lg ^ (brow1 & 3)) << 3);
  _Float16* dstA  = &As[(w * 16) * BK];
  _Float16* dstB0 = &Bs[(w * (NBI * 16)) * BK];
  _Float16* dstB1 = &Bs[(w * (NBI * 16) + 16) * BK];

  f32x4 acc[4][FN];
#pragma unroll
  for (int i = 0; i < 4; ++i)
#pragma unroll
    for (int j = 0; j < FN; ++j) acc[i][j] = (f32x4){0.f, 0.f, 0.f, 0.f};

  const int nsteps = K >> 5;

  auto stage = [&](int t, int buf) {
    const int kt = t << 5;
    GLD16(srcA + kt, dstA + buf * ASZ);
    GLD16(srcB0 + kt, dstB0 + buf * BSZ);
    if constexpr (NBI == 2) GLD16(srcB1 + kt, dstB1 + buf * BSZ);
  };

  stage(0, 0);
  if (nsteps > 1) stage(1, 1);

  int rbuf = 0;
  int wbuf = 2;
  for (int t = 0; t < nsteps; ++t) {
    if (t + 1 < nsteps) {
      if constexpr (NBI == 2) asm volatile("s_waitcnt vmcnt(3)" ::: "memory");
      else                    asm volatile("s_waitcnt vmcnt(2)" ::: "memory");
    } else {
      asm volatile("s_waitcnt vmcnt(0)" ::: "memory");
    }
    __builtin_amdgcn_sched_barrier(0);
    __builtin_amdgcn_s_barrier();
    __builtin_amdgcn_sched_barrier(0);

    if (t + 2 < nsteps) stage(t + 2, wbuf);

    const _Float16* as = As + rbuf * ASZ;
    const _Float16* bs = Bs + rbuf * BSZ;
    f16x8 a[4], b[FN];
#pragma unroll
    for (int i = 0; i < 4; ++i) {
      const int r = wm * 64 + i * 16 + l15;
      a[i] = *(const f16x8*)&as[r * BK + ((l16 ^ (r & 3)) << 3)];
    }
#pragma unroll
    for (int j = 0; j < FN; ++j) {
      const int n = wn * (FN * 16) + j * 16 + l15;
      b[j] = *(const f16x8*)&bs[n * BK + ((l16 ^ (n & 3)) << 3)];
    }
#pragma unroll
    for (int i = 0; i < 4; ++i)
#pragma unroll
      for (int j = 0; j < FN; ++j)
        acc[i][j] = __builtin_amdgcn_mfma_f32_16x16x32_f16(a[i], b[j], acc[i][j], 0, 0, 0);

    rbuf = (rbuf == 2) ? 0 : rbuf + 1;
    wbuf = (wbuf == 2) ? 0 : wbuf + 1;
  }
  __syncthreads();

  // ---------- epilogue: LDS-staged coalesced stores ----------
  constexpr int ESTR = BN + EPAD;
  constexpr int CPT  = BN / 16;
#pragma unroll
  for (int c = 0; c < 4; ++c) {
    if (wm == (c >> 1)) {
      const int ib = (c & 1) * 2;
#pragma unroll
      for (int ii = 0; ii < 2; ++ii) {
        const int i = ib + ii;
#pragma unroll
        for (int j = 0; j < FN; ++j) {
          const int col = wn * (FN * 16) + j * 16 + l15;
#pragma unroll
          for (int r = 0; r < 4; ++r) {
            const int lrow = ii * 16 + l16 * 4 + r;
            epi[lrow * ESTR + col] = acc[i][j][r];
          }
        }
      }
    }
    __syncthreads();
    {
      const int lrow = tid >> 4;
      const int grow = row0 + c * 32 + lrow;
      const int colb = (tid & 15) * CPT;
      if (grow < M) {
        float v[CPT];
#pragma unroll
        for (int q = 0; q < CPT; q += 4)
          *(float4*)&v[q] = *(const float4*)&epi[lrow * ESTR + colb + q];
        if constexpr (OUT_Y) {
          const float dv = dis[grow];
          f16x8 o[CPT / 8];
#pragma unroll
          for (int q = 0; q < CPT; ++q) o[q >> 3][q & 7] = (_Float16)(v[q] * dv);
#pragma unroll
          for (int q = 0; q < CPT / 8; ++q)
            *(f16x8*)(Y + (size_t)grow * BN + colb + q * 8) = o[q];
        } else {
#pragma unroll
          for (int q = 0; q < CPT; ++q) v[q] += bias[colb + q];
#pragma unroll
          for (int q = 0; q < CPT; q += 4)
            *(float4*)(C + (size_t)grow * BN + colb + q) = *(const float4*)&v[q];
        }
      }
    }
    __syncthreads();
  }
}

// ---------- gather-aggregate on pre-scaled f16 y-rows ----------
// h-stores nontemporal: don't let 50MB of output write-allocate evict y16.
__global__ __launch_bounds__(256) void gather_k(const _Float16* __restrict__ y,
                                                const int* __restrict__ ssorted,
                                                const int* __restrict__ off,
                                                const int* __restrict__ bsum,
                                                const float* __restrict__ dis,
                                                const float* __restrict__ bias,
                                                _Float16* __restrict__ h,
                                                int n, int E) {
  const int gid = blockIdx.x * 256 + threadIdx.x;
  const int v = gid >> 6, lane = gid & 63;
  if (v >= n) return;

  const float dv = dis[v];
  const int fo = lane * 4;

  f16x4 sv = *(const f16x4*)(y + (size_t)v * 256 + fo);  // self term y[v]
  float4 acc = make_float4((float)sv[0], (float)sv[1], (float)sv[2], (float)sv[3]);

  const int beg = off[v] + bsum[v >> 10];
  const int end = (v + 1 < n) ? (off[v + 1] + bsum[(v + 1) >> 10]) : E;
  const int ne = end - beg;

  for (int j0 = 0; j0 < ne; j0 += 64) {
    const int rem = ne - j0;
    const int cnt = rem < 64 ? rem : 64;
    int s_l = 0;
    if (lane < cnt) s_l = ssorted[beg + j0 + lane];

    int k = 0;
    for (; k + 8 <= cnt; k += 8) {
      f16x4 yv[8];
#pragma unroll
      for (int u = 0; u < 8; ++u) {
        const int s = __shfl(s_l, k + u);
        yv[u] = *(const f16x4*)(y + (size_t)s * 256 + fo);
      }
#pragma unroll
      for (int u = 0; u < 8; ++u) {
        acc.x += (float)yv[u][0];
        acc.y += (float)yv[u][1];
        acc.z += (float)yv[u][2];
        acc.w += (float)yv[u][3];
      }
    }
    for (; k < cnt; ++k) {
      const int s = __shfl(s_l, k);
      const f16x4 yv = *(const f16x4*)(y + (size_t)s * 256 + fo);
      acc.x += (float)yv[0];
      acc.y += (float)yv[1];
      acc.z += (float)yv[2];
      acc.w += (float)yv[3];
    }
  }

  const float4 b = *(const float4*)(bias + fo);
  f16x4 o;
  o[0] = (_Float16)fmaxf(fmaf(dv, acc.x, b.x), 0.f);
  o[1] = (_Float16)fmaxf(fmaf(dv, acc.y, b.y), 0.f);
  o[2] = (_Float16)fmaxf(fmaf(dv, acc.z, b.z), 0.f);
  o[3] = (_Float16)fmaxf(fmaf(dv, acc.w, b.w), 0.f);
  unsigned long long ov;
  __builtin_memcpy(&ov, &o, 8);
  __builtin_nontemporal_store(ov, (unsigned long long*)(h + (size_t)v * 256 + fo));
}

// ---------- launch ----------
extern "C" void kernel_launch(void* const* d_in, const int* in_sizes, int n_in,
                              void* d_out, int out_size, void* d_ws, size_t ws_size,
                              hipStream_t stream) {
  const float* x    = (const float*)d_in[0];
  const int*   ei   = (const int*)d_in[1];
  const float* W1   = (const float*)d_in[2];
  const float* b1   = (const float*)d_in[3];
  const float* W2   = (const float*)d_in[4];
  const float* b2   = (const float*)d_in[5];
  const float* fc_w = (const float*)d_in[6];
  const float* fc_b = (const float*)d_in[7];
  float* out = (float*)d_out;

  const int E = in_sizes[1] / 2;
  const int* src = ei;
  const int* dst = ei + E;
  const int N = N_NODES;

  // workspace layout (~219 MB)
  char* p = (char*)d_ws;
  int*   deg     = (int*)p;            p += (size_t)N * 4;
  float* dis     = (float*)p;          p += (size_t)N * 4;
  int*   off     = (int*)p;            p += (size_t)(N + 1) * 4;
  int*   pe      = (int*)p;            p += (size_t)E * 4;
  int*   ssorted = (int*)p;            p += (size_t)E * 4;
  int*   bsum    = (int*)p;            p += 512;
  p = (char*)(((size_t)p + 255) & ~(size_t)255);
  _Float16* w1t = (_Float16*)p;        p += (size_t)D_H   * D_IN * 2;
  _Float16* w2t = (_Float16*)p;        p += (size_t)D_H   * D_H  * 2;
  _Float16* fct = (_Float16*)p;        p += (size_t)D_OUT * D_H  * 2;
  p = (char*)(((size_t)p + 255) & ~(size_t)255);
  _Float16* x16 = (_Float16*)p;        p += (size_t)M_PAD * D_IN * 2;  // 102.5 MB
  _Float16* y16 = (_Float16*)p;        p += (size_t)M_PAD * D_H * 2;   // 51.25 MB
  _Float16* h16 = (_Float16*)p;        p += (size_t)M_PAD * D_H * 2;   // 51.25 MB

  // prep: x->f16 + weight transposes (one kernel); deg zero (own kernel)
  prep_k<<<CVT_BLOCKS + 896, 256, 0, stream>>>(x, x16, W1, W2, fc_w, w1t, w2t, fct);
  zero_deg_k<<<(N / 4 + 255) / 256, 256, 0, stream>>>(deg);

  // CSR build
  const int NB1 = (N + 1023) / 1024;   // 98
  const int EB4 = ((E + 3) / 4 + 255) / 256;
  deg_count_k<<<EB4, 256, 0, stream>>>(dst, deg, pe, E);
  scan1_k<<<NB1, 256, 0, stream>>>(deg, off, bsum, dis, N);
  scan2_k<<<1, 128, 0, stream>>>(bsum, NB1);
  fill_k<<<EB4, 256, 0, stream>>>(src, dst, pe, off, bsum, ssorted, E);

  const int node_wave_blocks = (N * 64 + 255) / 256;
  const dim3 gg(1, M_PAD / 128);  // 782

  // layer 1: y = dis * (x @ W1), f16
  gemm_glds_k<256, true><<<gg, 512, 0, stream>>>(
      x16, w1t, nullptr, dis, nullptr, y16, N, D_IN);
  gather_k<<<node_wave_blocks, 256, 0, stream>>>(y16, ssorted, off, bsum, dis, b1, h16, N, E);

  // layer 2: y = dis * (h1 @ W2), f16
  gemm_glds_k<256, true><<<gg, 512, 0, stream>>>(
      h16, w2t, nullptr, dis, nullptr, y16, N, D_H);
  gather_k<<<node_wave_blocks, 256, 0, stream>>>(y16, ssorted, off, bsum, dis, b2, h16, N, E);

  // final fc: out = h2 @ fc_w + fc_b (fp32)
  gemm_glds_k<128, false><<<gg, 512, 0, stream>>>(
      h16, fct, fc_b, nullptr, out, nullptr, N, D_H);
}

// Round 12
// 482.170 us; speedup vs baseline: 1.0588x; 1.0588x over previous
//
#include <hip/hip_runtime.h>

// GCN on MI355X.
// R2: CSR gather. R3-R10: f16 MFMA GEMM, glds triple-buffer counted-vmcnt.
// R11: memset-118us was a rocprof artifact (zero_deg gained nothing); NT store
// neutral -> reverted.
// R12: cvt_x pass DELETED -- gemm1 stages fp32 A via glds (205MB read once,
// src-preswizzled, rows clamped for OOB) and converts fp32->f16 at the
// ds_read->MFMA boundary. gemm1 = 2-phase dbuf (64KB); gemm2/fc keep tbuf
// counted-vmcnt. Gathers at L3-fabric roofline (119us each).

#define N_NODES 100000
constexpr int D_IN  = 512;
constexpr int D_H   = 256;
constexpr int D_OUT = 128;
constexpr int M_PAD = 100096;   // 782*128 (y16/h16 row padding for glds)

typedef _Float16 f16x8 __attribute__((ext_vector_type(8)));
typedef _Float16 f16x4 __attribute__((ext_vector_type(4)));
typedef float f32x4 __attribute__((ext_vector_type(4)));

#define GLD16(SRC, DST) __builtin_amdgcn_global_load_lds(                      \
    (const __attribute__((address_space(1))) void*)(SRC),                      \
    (__attribute__((address_space(3))) void*)(DST), 16, 0, 0)

// ---------- deg zero ----------
__global__ __launch_bounds__(256) void zero_deg_k(int* __restrict__ deg) {
  int i = (blockIdx.x * 256 + threadIdx.x) * 4;
  if (i < N_NODES) *(int4*)(deg + i) = make_int4(0, 0, 0, 0);  // N%4==0
}

// ---------- weight transposes (fp32 [K][N] -> f16 [N][K]) ----------
__global__ __launch_bounds__(256) void wtrans_k(const float* __restrict__ W1,
                                                const float* __restrict__ W2,
                                                const float* __restrict__ FC,
                                                _Float16* __restrict__ w1t,
                                                _Float16* __restrict__ w2t,
                                                _Float16* __restrict__ fct) {
  int i = blockIdx.x * 256 + threadIdx.x;
  if (i < 131072) {                       // W1: 512x256
    int k = i >> 8, n = i & 255;
    w1t[(size_t)n * 512 + k] = (_Float16)W1[i];
  } else if (i < 196608) {                // W2: 256x256
    int j = i - 131072;
    int k = j >> 8, n = j & 255;
    w2t[(size_t)n * 256 + k] = (_Float16)W2[j];
  } else if (i < 229376) {                // fc_w: 256x128
    int j = i - 196608;
    int k = j >> 7, n = j & 127;
    fct[(size_t)n * 256 + k] = (_Float16)FC[j];
  }
}

// ---------- CSR build ----------
__global__ __launch_bounds__(256) void deg_count_k(const int* __restrict__ dst,
                                                   int* __restrict__ deg,
                                                   int* __restrict__ pe, int E) {
  int i = (blockIdx.x * 256 + threadIdx.x) * 4;
  if (i + 3 < E) {
    int4 d = *(const int4*)(dst + i);
    int4 p;
    p.x = atomicAdd(&deg[d.x], 1);
    p.y = atomicAdd(&deg[d.y], 1);
    p.z = atomicAdd(&deg[d.z], 1);
    p.w = atomicAdd(&deg[d.w], 1);
    *(int4*)(pe + i) = p;
  } else {
    for (int t = i; t < E; ++t) pe[t] = atomicAdd(&deg[dst[t]], 1);
  }
}

__global__ __launch_bounds__(256) void scan1_k(const int* __restrict__ deg,
                                               int* __restrict__ off,
                                               int* __restrict__ bsum,
                                               float* __restrict__ dis, int n) {
  __shared__ int ts[256];
  const int tid = threadIdx.x;
  const int base = blockIdx.x * 1024 + tid * 4;
  int v[4];
#pragma unroll
  for (int t = 0; t < 4; ++t) v[t] = (base + t < n) ? deg[base + t] : 0;
#pragma unroll
  for (int t = 0; t < 4; ++t)
    if (base + t < n) dis[base + t] = rsqrtf((float)v[t] + 1.0f);
  const int tot = v[0] + v[1] + v[2] + v[3];
  ts[tid] = tot;
  __syncthreads();
  for (int o = 1; o < 256; o <<= 1) {
    int t = (tid >= o) ? ts[tid - o] : 0;
    __syncthreads();
    ts[tid] += t;
    __syncthreads();
  }
  int run = ts[tid] - tot;
#pragma unroll
  for (int t = 0; t < 4; ++t) {
    if (base + t < n) off[base + t] = run;
    run += v[t];
  }
  if (tid == 255) bsum[blockIdx.x] = ts[255];
}

__global__ __launch_bounds__(128) void scan2_k(int* __restrict__ bsum, int nb) {
  __shared__ int ts[128];
  const int tid = threadIdx.x;
  const int v = (tid < nb) ? bsum[tid] : 0;
  ts[tid] = v;
  __syncthreads();
  for (int o = 1; o < 128; o <<= 1) {
    int t = (tid >= o) ? ts[tid - o] : 0;
    __syncthreads();
    ts[tid] += t;
    __syncthreads();
  }
  if (tid < nb) bsum[tid] = ts[tid] - v;
}

__global__ __launch_bounds__(256) void fill_k(const int* __restrict__ src,
                                              const int* __restrict__ dst,
                                              const int* __restrict__ pe,
                                              const int* __restrict__ off,
                                              const int* __restrict__ bsum,
                                              int* __restrict__ ssorted, int E) {
  int i = (blockIdx.x * 256 + threadIdx.x) * 4;
  if (i + 3 < E) {
    int4 s = *(const int4*)(src + i);
    int4 d = *(const int4*)(dst + i);
    int4 p = *(const int4*)(pe + i);
    ssorted[off[d.x] + bsum[d.x >> 10] + p.x] = s.x;
    ssorted[off[d.y] + bsum[d.y >> 10] + p.y] = s.y;
    ssorted[off[d.z] + bsum[d.z >> 10] + p.z] = s.z;
    ssorted[off[d.w] + bsum[d.w >> 10] + p.w] = s.w;
  } else {
    for (int t = i; t < E; ++t) {
      int d = dst[t];
      ssorted[off[d] + bsum[d >> 10] + pe[t]] = src[t];
    }
  }
}

// ---------- glds f16 MFMA GEMM ----------
// AF32=true (layer 1): A fp32 glds-staged, converted f16 at ds_read; 2-phase dbuf.
// AF32=false: A f16 glds; triple-buffer counted-vmcnt (R10).
// OUT_Y: Y = dis[row]*(A@B) f16. else: C = A@B + bias, fp32.
template<int BN, bool AF32, bool OUT_Y>
__global__ __launch_bounds__(512, 4) void gemm_glds_k(
    const float* __restrict__ Af32,
    const _Float16* __restrict__ A16,
    const _Float16* __restrict__ Bt,
    const float* __restrict__ bias,
    const float* __restrict__ dis,
    float* __restrict__ C,
    _Float16* __restrict__ Y,
    int M, int K) {
  constexpr int BM = 128, BK = 32;
  constexpr int FN   = BN / 64;        // 4 (BN=256) or 2 (BN=128)
  constexpr int NBI  = BN / 128;       // B glds instrs per wave (2 or 1)
  constexpr int ASZ  = BM * BK;        // f16 elems per A buffer (f16 path)
  constexpr int AFSZ = BM * BK;        // f32 elems per A buffer (fp32 path)
  constexpr int BSZ  = BN * BK;        // f16 elems per B buffer
  constexpr int EPAD = 4;
  constexpr int SMEM_F16 = AF32 ? 2 * (2 * AFSZ + BSZ) : 3 * (ASZ + BSZ);

  __shared__ __align__(16) _Float16 smem[SMEM_F16];  // 64KB / 72KB / 48KB
  float* epi = (float*)smem;

  const int tid  = threadIdx.x;
  const int w    = tid >> 6, lane = tid & 63;
  const int wm   = w >> 2, wn = w & 3;
  const int l15  = lane & 15, l16 = lane >> 4;
  const int row0 = blockIdx.y * BM;

  f32x4 acc[4][FN];
#pragma unroll
  for (int i = 0; i < 4; ++i)
#pragma unroll
    for (int j = 0; j < FN; ++j) acc[i][j] = (f32x4){0.f, 0.f, 0.f, 0.f};

  const int nsteps = K >> 5;

  // ---- B mapping (shared by both paths): 16 rows x 64B per glds instr ----
  const int lr = lane >> 2, lg = lane & 3;
  const int brow0 = w * (NBI * 16) + lr;
  const int brow1 = brow0 + 16;
  const _Float16* srcB0 = Bt + (size_t)brow0 * K + ((lg ^ (brow0 & 3)) << 3);
  const _Float16* srcB1 = Bt + (size_t)brow1 * K + ((lg ^ (brow1 & 3)) << 3);

  if constexpr (AF32) {
    // ================= layer-1: fp32 A, 2-phase double buffer =================
    float* Asf = (float*)smem;                       // [2][AFSZ]
    _Float16* Bs = smem + 4 * AFSZ;                  // f16 offset past 2 f32 bufs
    // A mapping: 8 rows x 128B per glds instr, 2 instrs; lane -> row lane>>3,
    // 16B granule lane&7, source granule pre-XOR'd by (row&7).
    const int lr8 = lane >> 3, lg8 = lane & 7;
    const int ar0 = w * 16 + lr8, ar1 = ar0 + 8;
    int g0 = row0 + ar0; if (g0 >= M) g0 = M - 1;    // clamp: x not row-padded
    int g1 = row0 + ar1; if (g1 >= M) g1 = M - 1;
    const float* srcA0 = Af32 + (size_t)g0 * K + ((lg8 ^ (lr8 & 7)) << 2);
    const float* srcA1 = Af32 + (size_t)g1 * K + ((lg8 ^ (lr8 & 7)) << 2);
    float*    dA0 = Asf + (w * 16) * BK;
    float*    dA1 = dA0 + 8 * BK;
    _Float16* dB0 = &Bs[(w * (NBI * 16)) * BK];
    _Float16* dB1 = &Bs[(w * (NBI * 16) + 16) * BK];

    auto stage = [&](int t) {
      const int kt = t << 5;
      const int pa = (t & 1) * AFSZ, pb = (t & 1) * BSZ;
      GLD16(srcA0 + kt, dA0 + pa);
      GLD16(srcA1 + kt, dA1 + pa);
      GLD16(srcB0 + kt, dB0 + pb);
      if constexpr (NBI == 2) GLD16(srcB1 + kt, dB1 + pb);
    };

    stage(0);
    __syncthreads();
    for (int t = 0; t < nsteps; ++t) {
      if (t + 1 < nsteps) stage(t + 1);   // drained at the barrier below
      const float* as = Asf + (t & 1) * AFSZ;
      const _Float16* bs = Bs + (t & 1) * BSZ;
      f16x8 a[4], b[FN];
#pragma unroll
      for (int i = 0; i < 4; ++i) {
        const int r = wm * 64 + i * 16 + l15;
        const float* ar = as + r * BK;
        const int s = r & 7;
        float4 lo = *(const float4*)(ar + (((2 * l16) ^ s) << 2));
        float4 hi = *(const float4*)(ar + (((2 * l16 + 1) ^ s) << 2));
        a[i][0] = (_Float16)lo.x; a[i][1] = (_Float16)lo.y;
        a[i][2] = (_Float16)lo.z; a[i][3] = (_Float16)lo.w;
        a[i][4] = (_Float16)hi.x; a[i][5] = (_Float16)hi.y;
        a[i][6] = (_Float16)hi.z; a[i][7] = (_Float16)hi.w;
      }
#pragma unroll
      for (int j = 0; j < FN; ++j) {
        const int n = wn * (FN * 16) + j * 16 + l15;
        b[j] = *(const f16x8*)&bs[n * BK + ((l16 ^ (n & 3)) << 3)];
      }
#pragma unroll
      for (int i = 0; i < 4; ++i)
#pragma unroll
        for (int j = 0; j < FN; ++j)
          acc[i][j] = __builtin_amdgcn_mfma_f32_16x16x32_f16(a[i], b[j], acc[i][j], 0, 0, 0);
      __syncthreads();
    }
  } else {
    // ================= f16 A, triple buffer, counted vmcnt (R10) =============
    _Float16* As = smem;
    _Float16* Bs = smem + 3 * ASZ;
    const int arow = w * 16 + lr;
    const _Float16* srcA = A16 + (size_t)(row0 + arow) * K + ((lg ^ (arow & 3)) << 3);
    _Float16* dstA  = &As[(w * 16) * BK];
    _Float16* dstB0 = &Bs[(w * (NBI * 16)) * BK];
    _Float16* dstB1 = &Bs[(w * (NBI * 16) + 16) * BK];

    auto stage = [&](int t, int buf) {
      const int kt = t << 5;
      GLD16(srcA + kt, dstA + buf * ASZ);
      GLD16(srcB0 + kt, dstB0 + buf * BSZ);
      if constexpr (NBI == 2) GLD16(srcB1 + kt, dstB1 + buf * BSZ);
    };

    stage(0, 0);
    if (nsteps > 1) stage(1, 1);

    int rbuf = 0, wbuf = 2;
    for (int t = 0; t < nsteps; ++t) {
      if (t + 1 < nsteps) {
        if constexpr (NBI == 2) asm volatile("s_waitcnt vmcnt(3)" ::: "memory");
        else                    asm volatile("s_waitcnt vmcnt(2)" ::: "memory");
      } else {
        asm volatile("s_waitcnt vmcnt(0)" ::: "memory");
      }
      __builtin_amdgcn_sched_barrier(0);
      __builtin_amdgcn_s_barrier();
      __builtin_amdgcn_sched_barrier(0);

      if (t + 2 < nsteps) stage(t + 2, wbuf);

      const _Float16* as = As + rbuf * ASZ;
      const _Float16* bs = Bs + rbuf * BSZ;
      f16x8 a[4], b[FN];
#pragma unroll
      for (int i = 0; i < 4; ++i) {
        const int r = wm * 64 + i * 16 + l15;
        a[i] = *(const f16x8*)&as[r * BK + ((l16 ^ (r & 3)) << 3)];
      }
#pragma unroll
      for (int j = 0; j < FN; ++j) {
        const int n = wn * (FN * 16) + j * 16 + l15;
        b[j] = *(const f16x8*)&bs[n * BK + ((l16 ^ (n & 3)) << 3)];
      }
#pragma unroll
      for (int i = 0; i < 4; ++i)
#pragma unroll
        for (int j = 0; j < FN; ++j)
          acc[i][j] = __builtin_amdgcn_mfma_f32_16x16x32_f16(a[i], b[j], acc[i][j], 0, 0, 0);

      rbuf = (rbuf == 2) ? 0 : rbuf + 1;
      wbuf = (wbuf == 2) ? 0 : wbuf + 1;
    }
    __syncthreads();
  }

  // ---------- epilogue: LDS-staged coalesced stores ----------
  constexpr int ESTR = BN + EPAD;
  constexpr int CPT  = BN / 16;
#pragma unroll
  for (int c = 0; c < 4; ++c) {
    if (wm == (c >> 1)) {
      const int ib = (c & 1) * 2;
#pragma unroll
      for (int ii = 0; ii < 2; ++ii) {
        const int i = ib + ii;
#pragma unroll
        for (int j = 0; j < FN; ++j) {
          const int col = wn * (FN * 16) + j * 16 + l15;
#pragma unroll
          for (int r = 0; r < 4; ++r) {
            const int lrow = ii * 16 + l16 * 4 + r;
            epi[lrow * ESTR + col] = acc[i][j][r];
          }
        }
      }
    }
    __syncthreads();
    {
      const int lrow = tid >> 4;
      const int grow = row0 + c * 32 + lrow;
      const int colb = (tid & 15) * CPT;
      if (grow < M) {
        float v[CPT];
#pragma unroll
        for (int q = 0; q < CPT; q += 4)
          *(float4*)&v[q] = *(const float4*)&epi[lrow * ESTR + colb + q];
        if constexpr (OUT_Y) {
          const float dv = dis[grow];
          f16x8 o[CPT / 8];
#pragma unroll
          for (int q = 0; q < CPT; ++q) o[q >> 3][q & 7] = (_Float16)(v[q] * dv);
#pragma unroll
          for (int q = 0; q < CPT / 8; ++q)
            *(f16x8*)(Y + (size_t)grow * BN + colb + q * 8) = o[q];
        } else {
#pragma unroll
          for (int q = 0; q < CPT; ++q) v[q] += bias[colb + q];
#pragma unroll
          for (int q = 0; q < CPT; q += 4)
            *(float4*)(C + (size_t)grow * BN + colb + q) = *(const float4*)&v[q];
        }
      }
    }
    __syncthreads();
  }
}

// ---------- gather-aggregate on pre-scaled f16 y-rows ----------
__global__ __launch_bounds__(256) void gather_k(const _Float16* __restrict__ y,
                                                const int* __restrict__ ssorted,
                                                const int* __restrict__ off,
                                                const int* __restrict__ bsum,
                                                const float* __restrict__ dis,
                                                const float* __restrict__ bias,
                                                _Float16* __restrict__ h,
                                                int n, int E) {
  const int gid = blockIdx.x * 256 + threadIdx.x;
  const int v = gid >> 6, lane = gid & 63;
  if (v >= n) return;

  const float dv = dis[v];
  const int fo = lane * 4;

  f16x4 sv = *(const f16x4*)(y + (size_t)v * 256 + fo);  // self term y[v]
  float4 acc = make_float4((float)sv[0], (float)sv[1], (float)sv[2], (float)sv[3]);

  const int beg = off[v] + bsum[v >> 10];
  const int end = (v + 1 < n) ? (off[v + 1] + bsum[(v + 1) >> 10]) : E;
  const int ne = end - beg;

  for (int j0 = 0; j0 < ne; j0 += 64) {
    const int rem = ne - j0;
    const int cnt = rem < 64 ? rem : 64;
    int s_l = 0;
    if (lane < cnt) s_l = ssorted[beg + j0 + lane];

    int k = 0;
    for (; k + 8 <= cnt; k += 8) {
      f16x4 yv[8];
#pragma unroll
      for (int u = 0; u < 8; ++u) {
        const int s = __shfl(s_l, k + u);
        yv[u] = *(const f16x4*)(y + (size_t)s * 256 + fo);
      }
#pragma unroll
      for (int u = 0; u < 8; ++u) {
        acc.x += (float)yv[u][0];
        acc.y += (float)yv[u][1];
        acc.z += (float)yv[u][2];
        acc.w += (float)yv[u][3];
      }
    }
    for (; k < cnt; ++k) {
      const int s = __shfl(s_l, k);
      const f16x4 yv = *(const f16x4*)(y + (size_t)s * 256 + fo);
      acc.x += (float)yv[0];
      acc.y += (float)yv[1];
      acc.z += (float)yv[2];
      acc.w += (float)yv[3];
    }
  }

  const float4 b = *(const float4*)(bias + fo);
  f16x4 o;
  o[0] = (_Float16)fmaxf(fmaf(dv, acc.x, b.x), 0.f);
  o[1] = (_Float16)fmaxf(fmaf(dv, acc.y, b.y), 0.f);
  o[2] = (_Float16)fmaxf(fmaf(dv, acc.z, b.z), 0.f);
  o[3] = (_Float16)fmaxf(fmaf(dv, acc.w, b.w), 0.f);
  *(f16x4*)(h + (size_t)v * 256 + fo) = o;
}

// ---------- launch ----------
extern "C" void kernel_launch(void* const* d_in, const int* in_sizes, int n_in,
                              void* d_out, int out_size, void* d_ws, size_t ws_size,
                              hipStream_t stream) {
  const float* x    = (const float*)d_in[0];
  const int*   ei   = (const int*)d_in[1];
  const float* W1   = (const float*)d_in[2];
  const float* b1   = (const float*)d_in[3];
  const float* W2   = (const float*)d_in[4];
  const float* b2   = (const float*)d_in[5];
  const float* fc_w = (const float*)d_in[6];
  const float* fc_b = (const float*)d_in[7];
  float* out = (float*)d_out;

  const int E = in_sizes[1] / 2;
  const int* src = ei;
  const int* dst = ei + E;
  const int N = N_NODES;

  // workspace layout (~117 MB)
  char* p = (char*)d_ws;
  int*   deg     = (int*)p;            p += (size_t)N * 4;
  float* dis     = (float*)p;          p += (size_t)N * 4;
  int*   off     = (int*)p;            p += (size_t)(N + 1) * 4;
  int*   pe      = (int*)p;            p += (size_t)E * 4;
  int*   ssorted = (int*)p;            p += (size_t)E * 4;
  int*   bsum    = (int*)p;            p += 512;
  p = (char*)(((size_t)p + 255) & ~(size_t)255);
  _Float16* w1t = (_Float16*)p;        p += (size_t)D_H   * D_IN * 2;
  _Float16* w2t = (_Float16*)p;        p += (size_t)D_H   * D_H  * 2;
  _Float16* fct = (_Float16*)p;        p += (size_t)D_OUT * D_H  * 2;
  p = (char*)(((size_t)p + 255) & ~(size_t)255);
  _Float16* y16 = (_Float16*)p;        p += (size_t)M_PAD * D_H * 2;   // 51.25 MB
  _Float16* h16 = (_Float16*)p;        p += (size_t)M_PAD * D_H * 2;   // 51.25 MB

  // weights + deg zero
  wtrans_k<<<896, 256, 0, stream>>>(W1, W2, fc_w, w1t, w2t, fct);
  zero_deg_k<<<(N / 4 + 255) / 256, 256, 0, stream>>>(deg);

  // CSR build
  const int NB1 = (N + 1023) / 1024;   // 98
  const int EB4 = ((E + 3) / 4 + 255) / 256;
  deg_count_k<<<EB4, 256, 0, stream>>>(dst, deg, pe, E);
  scan1_k<<<NB1, 256, 0, stream>>>(deg, off, bsum, dis, N);
  scan2_k<<<1, 128, 0, stream>>>(bsum, NB1);
  fill_k<<<EB4, 256, 0, stream>>>(src, dst, pe, off, bsum, ssorted, E);

  const int node_wave_blocks = (N * 64 + 255) / 256;
  const dim3 gg(1, M_PAD / 128);  // 782

  // layer 1: y = dis * (x @ W1), fp32 A staged+converted in-kernel
  gemm_glds_k<256, true, true><<<gg, 512, 0, stream>>>(
      x, nullptr, w1t, nullptr, dis, nullptr, y16, N, D_IN);
  gather_k<<<node_wave_blocks, 256, 0, stream>>>(y16, ssorted, off, bsum, dis, b1, h16, N, E);

  // layer 2: y = dis * (h1 @ W2), f16 A
  gemm_glds_k<256, false, true><<<gg, 512, 0, stream>>>(
      nullptr, h16, w2t, nullptr, dis, nullptr, y16, N, D_H);
  gather_k<<<node_wave_blocks, 256, 0, stream>>>(y16, ssorted, off, bsum, dis, b2, h16, N, E);

  // final fc: out = h2 @ fc_w + fc_b (fp32)
  gemm_glds_k<128, false, false><<<gg, 512, 0, stream>>>(
      nullptr, h16, fct, fc_b, nullptr, out, nullptr, N, D_H);
}